// Round 8
// baseline (23282.089 us; speedup 1.0000x reference)
//
#include <hip/hip_runtime.h>
#include <hip/hip_cooperative_groups.h>

namespace cg = cooperative_groups;

// R18: dual-direction intra-WG pipeline. 256 WGs x 512 thr (1/CU).
// WG = (bg of 8 batches, 8-cell slice, BOTH dirs). Per iteration the WG
// advances fwd step t=s and bwd step t=Tv-1-s. The two recurrences are
// independent, so each one's flag-propagation latency (release at end of
// iter s-1 -> poll in iter s) is hidden under the OTHER work: both
// x-GEMMs + x-prefetch run before the poll. R17 showed wave-level
// run-ahead on ONE pipeline can't hide this latency; two pipelines can,
// deterministically. Register budget == R15 (acc 32 + whr 64 VGPR);
// quad pre-reduce is IN-PLACE shfl (R16's spill was the v[32] copy).
// Flags: packed 4B slots, plain release stores, pollers = tail waves 0-1.
// h exchange through `out` (sc1 publish, fresh-address cached reads).

#define Bv 32
#define Tv 512
#define Dv 512
#define Hv 512
#define XS 520            // x LDS row stride
#define HS 520            // h LDS row stride (union with part[256*9])

__device__ __forceinline__ float sigmf_(float x) { return 1.0f / (1.0f + __expf(-x)); }
__device__ __forceinline__ float tanhf_(float x) { return 2.0f / (1.0f + __expf(-2.0f * x)) - 1.0f; }

__global__ __launch_bounds__(512, 2) void bilstm_coop8(
    const float* __restrict__ x, const int* __restrict__ lengths,
    const float* __restrict__ Wih_f, const float* __restrict__ Whh_f,
    const float* __restrict__ bih_f, const float* __restrict__ bhh_f,
    const float* __restrict__ Wih_b, const float* __restrict__ Whh_b,
    const float* __restrict__ bih_b, const float* __restrict__ bhh_b,
    float* __restrict__ out, unsigned int* __restrict__ cnt)  // cnt: 8 groups x 64 u32
{
    __shared__ float xbF[2][8 * XS];   // 33.3 KB
    __shared__ float xbB[2][8 * XS];   // 33.3 KB
    __shared__ float huF[8 * HS];      // 16.6 KB, union: partF[256*9]
    __shared__ float huB[8 * HS];      // 16.6 KB, union: partB[256*9]
    __shared__ float gatesF[32 * 9];
    __shared__ float gatesB[32 * 9];
    __shared__ float biasF[32], biasB[32];

    const int tid = threadIdx.x;
    const int w   = blockIdx.x;

    // blockIdx -> XCD = w & 7. Each XCD hosts cslices 8k..8k+7 (all 4 bgs):
    // resident Wih slice = 2 dirs x 256 rows x 512 x 4B = 1 MB -> L2-stable.
    const int xcd    = w & 7;
    const int slot   = w >> 3;                 // 0..31
    const int bg     = slot >> 3;              // 0..3
    const int cslice = xcd * 8 + (slot & 7);   // 0..63
    const int c0     = cslice * 8;             // first of 8 cells
    const int b0     = bg * 8;                 // first of 8 batches

    unsigned int* slotF = cnt + (size_t)(0 * 4 + bg) * 64 + cslice;
    unsigned int* slotB = cnt + (size_t)(1 * 4 + bg) * 64 + cslice;

    // ---- prologue ----
    if (tid == 0) {
        __hip_atomic_store(slotF, 0u, __ATOMIC_RELAXED, __HIP_MEMORY_SCOPE_AGENT);
        __hip_atomic_store(slotB, 0u, __ATOMIC_RELAXED, __HIP_MEMORY_SCOPE_AGENT);
    }
    if (tid < 32) {                       // biasF
        int gate = tid >> 3, cell = tid & 7;
        int rg = gate * Hv + c0 + cell;
        biasF[tid] = bih_f[rg] + bhh_f[rg];
    } else if (tid < 64) {                // biasB
        int i = tid - 32;
        int gate = i >> 3, cell = i & 7;
        int rg = gate * Hv + c0 + cell;
        biasB[i] = bih_b[rg] + bhh_b[rg];
    }
    // stage x(s=0) for both dirs into buffer 0
    #pragma unroll
    for (int j = 0; j < 2; ++j) {
        int F  = tid + j * 512;
        int bl = F >> 7, cf = F & 127;
        *(float4*)(&xbF[0][bl * XS + cf * 4]) =
            *(const float4*)(x + ((size_t)(b0 + bl) * Tv + 0) * Dv + cf * 4);
        *(float4*)(&xbB[0][bl * XS + cf * 4]) =
            *(const float4*)(x + ((size_t)(b0 + bl) * Tv + (Tv - 1)) * Dv + cf * 4);
    }
    cg::this_grid().sync();   // once per launch

    // thread tile: pos = 2 gate-rows per dir, 8 batches, 32-float k-segment
    const int pos  = tid >> 5;      // 0..15
    const int kseg = tid & 31;      // 0..31

    int wrF0, wrF1;                 // global W row indices (rows pos*2, pos*2+1)
    {
        int r0 = pos * 2, r1 = pos * 2 + 1;
        wrF0 = (r0 >> 3) * Hv + c0 + (r0 & 7);
        wrF1 = (r1 >> 3) * Hv + c0 + (r1 & 7);
    }
    // same row pattern for both dirs (different weight matrices)

    // step-invariant Whh slices in registers: 8 f4 per dir (64 VGPR total)
    float4 whrF[4][2], whrB[4][2];
    #pragma unroll
    for (int j = 0; j < 4; ++j) {
        const int col = (j * 32 + kseg) * 4;
        whrF[j][0] = *(const float4*)(Whh_f + (size_t)wrF0 * Dv + col);
        whrF[j][1] = *(const float4*)(Whh_f + (size_t)wrF1 * Dv + col);
        whrB[j][0] = *(const float4*)(Whh_b + (size_t)wrF0 * Dv + col);
        whrB[j][1] = *(const float4*)(Whh_b + (size_t)wrF1 * Dv + col);
    }

    // tail state: tid<64 -> fwd cell (ib=tid>>3, cell=tid&7); tid 64..127 -> bwd
    float cst_r = 0.0f;
    int   len_r = 0;
    if (tid < 64)        len_r = lengths[b0 + (tid >> 3)];
    else if (tid < 128)  len_r = lengths[b0 + ((tid - 64) >> 3)];

    float* partF = huF;   // aliases (dump fits: 256*9*4B = 9.2KB < 16.6KB)
    float* partB = huB;

    for (int s = 0; s < Tv; ++s) {
        const int tf  = s;
        const int tb  = Tv - 1 - s;
        const int cur = s & 1;

        // ---- 1. x-GEMMs (cover flag propagation from iter s-1) ----
        float accF[2][8], accB[2][8];
        #pragma unroll
        for (int ib = 0; ib < 8; ++ib) {
            accF[0][ib] = 0.f; accF[1][ib] = 0.f;
            accB[0][ib] = 0.f; accB[1][ib] = 0.f;
        }
        #pragma unroll
        for (int j = 0; j < 4; ++j) {
            const int col = (j * 32 + kseg) * 4;
            float4 wf0 = *(const float4*)(Wih_f + (size_t)wrF0 * Dv + col);
            float4 wf1 = *(const float4*)(Wih_f + (size_t)wrF1 * Dv + col);
            float4 wb0 = *(const float4*)(Wih_b + (size_t)wrF0 * Dv + col);
            float4 wb1 = *(const float4*)(Wih_b + (size_t)wrF1 * Dv + col);
            #pragma unroll
            for (int ib = 0; ib < 8; ++ib) {
                float4 xf = *(const float4*)(&xbF[cur][ib * XS + col]);
                float4 xv = *(const float4*)(&xbB[cur][ib * XS + col]);
                accF[0][ib] += wf0.x*xf.x + wf0.y*xf.y + wf0.z*xf.z + wf0.w*xf.w;
                accF[1][ib] += wf1.x*xf.x + wf1.y*xf.y + wf1.z*xf.z + wf1.w*xf.w;
                accB[0][ib] += wb0.x*xv.x + wb0.y*xv.y + wb0.z*xv.z + wb0.w*xv.w;
                accB[1][ib] += wb1.x*xv.x + wb1.y*xv.y + wb1.z*xv.z + wb1.w*xv.w;
            }
        }

        // ---- 2. prefetch x(s+1) for both dirs ----
        if (s + 1 < Tv) {
            const int tfn = s + 1, tbn = Tv - 2 - s;
            #pragma unroll
            for (int j = 0; j < 2; ++j) {
                int F  = tid + j * 512;
                int bl = F >> 7, cf = F & 127;
                *(float4*)(&xbF[cur ^ 1][bl * XS + cf * 4]) =
                    *(const float4*)(x + ((size_t)(b0 + bl) * Tv + tfn) * Dv + cf * 4);
                *(float4*)(&xbB[cur ^ 1][bl * XS + cf * 4]) =
                    *(const float4*)(x + ((size_t)(b0 + bl) * Tv + tbn) * Dv + cf * 4);
            }
        }

        // ---- 3. poll (tail waves double as pollers) ----
        if (s > 0 && tid < 128) {
            const unsigned int tgt = (unsigned int)s;
            const unsigned int* sl = (tid < 64)
                ? cnt + (size_t)(0 * 4 + bg) * 64 + tid
                : cnt + (size_t)(1 * 4 + bg) * 64 + (tid - 64);
            while (__hip_atomic_load(sl, __ATOMIC_RELAXED,
                                     __HIP_MEMORY_SCOPE_AGENT) < tgt)
                __builtin_amdgcn_s_sleep(1);
        }
        __syncthreads();   // [B]

        // ---- 4. stage h_{prev} for both dirs (fresh addresses -> LLC) ----
        if (s == 0) {
            #pragma unroll
            for (int j = 0; j < 2; ++j) {
                int F  = tid + j * 512;
                int bl = F >> 7, cf = F & 127;
                *(float4*)(huF + bl * HS + cf * 4) = make_float4(0.f,0.f,0.f,0.f);
                *(float4*)(huB + bl * HS + cf * 4) = make_float4(0.f,0.f,0.f,0.f);
            }
        } else {
            const int tfp = tf - 1, tbp = tb + 1;
            #pragma unroll
            for (int j = 0; j < 2; ++j) {
                int F  = tid + j * 512;
                int bl = F >> 7, cf = F & 127;
                *(float4*)(huF + bl * HS + cf * 4) =
                    *(const float4*)(out + ((size_t)(b0 + bl) * Tv + tfp) * (2 * Hv)
                                         + cf * 4);
                *(float4*)(huB + bl * HS + cf * 4) =
                    *(const float4*)(out + ((size_t)(b0 + bl) * Tv + tbp) * (2 * Hv)
                                         + Hv + cf * 4);
            }
        }
        __syncthreads();   // [C]

        // ---- 5. hold values (before hu is aliased as part) ----
        float hpv = 0.0f;
        if (tid < 64)        hpv = huF[(tid >> 3) * HS + c0 + (tid & 7)];
        else if (tid < 128)  hpv = huB[((tid - 64) >> 3) * HS + c0 + ((tid - 64) & 7)];

        // ---- 6. h-GEMMs (register weights + LDS) ----
        #pragma unroll
        for (int j = 0; j < 4; ++j) {
            const int col = (j * 32 + kseg) * 4;
            #pragma unroll
            for (int ib = 0; ib < 8; ++ib) {
                float4 hf = *(const float4*)(huF + ib * HS + col);
                float4 hb = *(const float4*)(huB + ib * HS + col);
                accF[0][ib] += whrF[j][0].x*hf.x + whrF[j][0].y*hf.y
                             + whrF[j][0].z*hf.z + whrF[j][0].w*hf.w;
                accF[1][ib] += whrF[j][1].x*hf.x + whrF[j][1].y*hf.y
                             + whrF[j][1].z*hf.z + whrF[j][1].w*hf.w;
                accB[0][ib] += whrB[j][0].x*hb.x + whrB[j][0].y*hb.y
                             + whrB[j][0].z*hb.z + whrB[j][0].w*hb.w;
                accB[1][ib] += whrB[j][1].x*hb.x + whrB[j][1].y*hb.y
                             + whrB[j][1].z*hb.z + whrB[j][1].w*hb.w;
            }
        }
        __syncthreads();   // [D] hu reads + hpv done; alias as part[256][9]

        // ---- 7. IN-PLACE quad pre-reduce (kseg^1, kseg^2) + dump ----
        #pragma unroll
        for (int i = 0; i < 2; ++i)
            #pragma unroll
            for (int ib = 0; ib < 8; ++ib) {
                float vF = accF[i][ib];
                vF += __shfl_xor(vF, 1, 64);
                vF += __shfl_xor(vF, 2, 64);
                accF[i][ib] = vF;
                float vB = accB[i][ib];
                vB += __shfl_xor(vB, 1, 64);
                vB += __shfl_xor(vB, 2, 64);
                accB[i][ib] = vB;
            }
        if ((kseg & 3) == 0) {
            const int q = kseg >> 2;
            #pragma unroll
            for (int i = 0; i < 2; ++i) {
                const int r = pos * 2 + i;
                #pragma unroll
                for (int ib = 0; ib < 8; ++ib) {
                    partF[(r * 8 + ib) * 9 + q] = accF[i][ib];
                    partB[(r * 8 + ib) * 9 + q] = accB[i][ib];
                }
            }
        }
        __syncthreads();   // [E]

        // ---- 8. final reduce (8 quads) + bias -> gates ----
        if (tid < 256) {
            const float* pr = partF + tid * 9;
            float s0 = (pr[0]+pr[1]) + (pr[2]+pr[3]);
            float s1 = (pr[4]+pr[5]) + (pr[6]+pr[7]);
            gatesF[(tid >> 3) * 9 + (tid & 7)] = s0 + s1 + biasF[tid >> 3];
        } else {
            const int i2 = tid - 256;
            const float* pr = partB + i2 * 9;
            float s0 = (pr[0]+pr[1]) + (pr[2]+pr[3]);
            float s1 = (pr[4]+pr[5]) + (pr[6]+pr[7]);
            gatesB[(i2 >> 3) * 9 + (i2 & 7)] = s0 + s1 + biasB[i2 >> 3];
        }
        __syncthreads();   // [F]

        // ---- 9. tails: fwd on tid<64, bwd on tid 64..127 ----
        if (tid < 64) {
            const int ib = tid >> 3, cell = tid & 7;
            float gi = sigmf_(gatesF[( 0 + cell) * 9 + ib]);
            float gf = sigmf_(gatesF[( 8 + cell) * 9 + ib]);
            float gg = tanhf_(gatesF[(16 + cell) * 9 + ib]);
            float go = sigmf_(gatesF[(24 + cell) * 9 + ib]);
            float cn = gf * cst_r + gi * gg;
            float hn = go * tanhf_(cn);
            const bool vld = (tf < len_r);
            float ho = vld ? hn : hpv;
            cst_r = vld ? cn : cst_r;
            __hip_atomic_store(out + ((size_t)(b0 + ib) * Tv + tf) * (2 * Hv)
                                   + c0 + cell,
                               ho, __ATOMIC_RELAXED, __HIP_MEMORY_SCOPE_AGENT);
        } else if (tid < 128) {
            const int i2 = tid - 64;
            const int ib = i2 >> 3, cell = i2 & 7;
            float gi = sigmf_(gatesB[( 0 + cell) * 9 + ib]);
            float gf = sigmf_(gatesB[( 8 + cell) * 9 + ib]);
            float gg = tanhf_(gatesB[(16 + cell) * 9 + ib]);
            float go = sigmf_(gatesB[(24 + cell) * 9 + ib]);
            float cn = gf * cst_r + gi * gg;
            float hn = go * tanhf_(cn);
            const bool vld = (tb < len_r);
            float ho = vld ? hn : hpv;
            cst_r = vld ? cn : cst_r;
            __hip_atomic_store(out + ((size_t)(b0 + ib) * Tv + tb) * (2 * Hv)
                                   + Hv + c0 + cell,
                               ho, __ATOMIC_RELAXED, __HIP_MEMORY_SCOPE_AGENT);
        }
        // ---- 10. releases (wave 0 covers F stores, wave 1 covers B) ----
        if (tid == 0)
            __hip_atomic_store(slotF, (unsigned int)(s + 1),
                               __ATOMIC_RELEASE, __HIP_MEMORY_SCOPE_AGENT);
        if (tid == 64)
            __hip_atomic_store(slotB, (unsigned int)(s + 1),
                               __ATOMIC_RELEASE, __HIP_MEMORY_SCOPE_AGENT);
        // no trailing sync: hazards gated by next iter's [B] (pollers are
        // the tail waves, so sprinters can't pass [B] before tails finish).
    }
}

// ---------------- fallback: R10 kernel (unchanged, correct, slow) ----------------
__global__ __launch_bounds__(1024, 1) void bilstm_simple(
    const float* __restrict__ x,
    const int* __restrict__ lengths,
    const float* __restrict__ Wih_f, const float* __restrict__ Whh_f,
    const float* __restrict__ bih_f, const float* __restrict__ bhh_f,
    const float* __restrict__ Wih_b, const float* __restrict__ Whh_b,
    const float* __restrict__ bih_b, const float* __restrict__ bhh_b,
    float* __restrict__ out)
{
    __shared__ float xh[Dv + Hv];
    __shared__ float cst[Hv];
    __shared__ float gates[4 * Hv];
    __shared__ float bias[4 * Hv];

    const int tid  = threadIdx.x;
    const int wave = tid >> 6;
    const int lane = tid & 63;
    const int dir  = blockIdx.x >> 5;
    const int b    = blockIdx.x & 31;

    const float* Wih = dir ? Wih_b : Wih_f;
    const float* Whh = dir ? Whh_b : Whh_f;
    const float* bih = dir ? bih_b : bih_f;
    const float* bhh = dir ? bhh_b : bhh_f;

    for (int i = tid; i < 4 * Hv; i += 1024) bias[i] = bih[i] + bhh[i];
    for (int i = tid; i < Hv; i += 1024) { xh[Dv + i] = 0.f; cst[i] = 0.f; }
    const int len = lengths[b];

    const float* Wbase = (lane < 32) ? Wih : Whh;
    const int koff = (lane & 31) * 16;

    for (int s = 0; s < Tv; ++s) {
        const int t = dir ? (Tv - 1 - s) : s;
        __syncthreads();
        for (int i = tid; i < Dv; i += 1024)
            xh[i] = x[((size_t)b * Tv + t) * Dv + i];
        __syncthreads();

        float4 xr0 = *(const float4*)(xh + lane * 16 + 0);
        float4 xr1 = *(const float4*)(xh + lane * 16 + 4);
        float4 xr2 = *(const float4*)(xh + lane * 16 + 8);
        float4 xr3 = *(const float4*)(xh + lane * 16 + 12);

        #pragma unroll 4
        for (int rr = 0; rr < 128; ++rr) {
            const int row = wave * 128 + rr;
            const float4* wr = (const float4*)(Wbase + (size_t)row * 512 + koff);
            const float4 w0 = wr[0], w1 = wr[1], w2 = wr[2], w3 = wr[3];
            float acc = w0.x * xr0.x + w0.y * xr0.y + w0.z * xr0.z + w0.w * xr0.w
                      + w1.x * xr1.x + w1.y * xr1.y + w1.z * xr1.z + w1.w * xr1.w
                      + w2.x * xr2.x + w2.y * xr2.y + w2.z * xr2.z + w2.w * xr2.w
                      + w3.x * xr3.x + w3.y * xr3.y + w3.z * xr3.z + w3.w * xr3.w;
            #pragma unroll
            for (int off = 32; off > 0; off >>= 1)
                acc += __shfl_xor(acc, off, 64);
            if (lane == 0) gates[row] = acc;
        }
        __syncthreads();

        if (tid < Hv) {
            const int cc = tid;
            const float gi = sigmf_(gates[0 * Hv + cc] + bias[0 * Hv + cc]);
            const float gf = sigmf_(gates[1 * Hv + cc] + bias[1 * Hv + cc]);
            const float gg = tanhf_(gates[2 * Hv + cc] + bias[2 * Hv + cc]);
            const float go = sigmf_(gates[3 * Hv + cc] + bias[3 * Hv + cc]);
            const float cn = gf * cst[cc] + gi * gg;
            const float hn = go * tanhf_(cn);
            const bool v = (t < len);
            const float hnew = v ? hn : xh[Dv + cc];
            cst[cc] = v ? cn : cst[cc];
            xh[Dv + cc] = hnew;
            out[((size_t)b * Tv + t) * (2 * Hv) + dir * Hv + cc] = hnew;
        }
    }
}

extern "C" void kernel_launch(void* const* d_in, const int* in_sizes, int n_in,
                              void* d_out, int out_size, void* d_ws, size_t ws_size,
                              hipStream_t stream) {
    (void)out_size;

    const void *xv, *len_p, *Wihf, *Whhf, *bihf, *bhhf, *Wihb, *Whhb, *bihb, *bhhb;
    if (n_in == 10 && in_sizes[9] == 8388608 && in_sizes[8] == 32) {
        // alphabetical pytree order fallback
        Whhb = d_in[0]; Whhf = d_in[1]; Wihb = d_in[2]; Wihf = d_in[3];
        bhhb = d_in[4]; bhhf = d_in[5]; bihb = d_in[6]; bihf = d_in[7];
        len_p = d_in[8]; xv = d_in[9];
    } else {
        // documented dict order
        xv = d_in[0]; len_p = d_in[1];
        Wihf = d_in[2]; Whhf = d_in[3]; bihf = d_in[4]; bhhf = d_in[5];
        Wihb = d_in[6]; Whhb = d_in[7]; bihb = d_in[8]; bhhb = d_in[9];
    }

    const float* xf  = (const float*)xv;
    const int*   lp  = (const int*)len_p;
    const float* wif = (const float*)Wihf;  const float* whf = (const float*)Whhf;
    const float* bif = (const float*)bihf;  const float* bhf = (const float*)bhhf;
    const float* wib = (const float*)Wihb;  const float* whb = (const float*)Whhb;
    const float* bib = (const float*)bihb;  const float* bhb = (const float*)bhhb;
    float* outp = (float*)d_out;
    unsigned int* cntp = (unsigned int*)d_ws;

    if (ws_size >= 8 * 64 * sizeof(unsigned int)) {   // 2 KB of slots
        void* args[12] = { &xf, &lp, &wif, &whf, &bif, &bhf,
                           &wib, &whb, &bib, &bhb, &outp, &cntp };
        hipError_t e = hipLaunchCooperativeKernel((const void*)bilstm_coop8,
                                                  dim3(256), dim3(512),
                                                  args, 0, stream);
        if (e == hipSuccess) return;
    }

    // fallback: R10 kernel
    bilstm_simple<<<dim3(64), dim3(1024), 0, stream>>>(
        xf, lp, wif, whf, bif, bhf, wib, whb, bib, bhb, outp);
}

// Round 10
// 9889.770 us; speedup vs baseline: 2.3542x; 2.3542x over previous
//
#include <hip/hip_runtime.h>
#include <hip/hip_cooperative_groups.h>

namespace cg = cooperative_groups;

// R20: R15's exact structure + XCD-LOCAL exchange. Each (dir,bg) pipeline
// group = 32 WGs = one full XCD (group id == w&7), so h exchange and flags
// live in the SHARED per-XCD L2 instead of the LLC:
//   - h publish: plain cached stores (dirty lines in shared L2)
//   - flag: plain store to shared L2, polled with inline-asm sc0 loads
//   - safety net (if w&7 mapping is wrong): arrive also does a RELEASE
//     agent store (wbl2 -> LLC current) and pollers do an agent-scope
//     load every 64 spins -> degrades to R15's LLC path, never hangs.
// Register budget, phase order, sync count identical to R15 (R16/R18: more
// regs => spill; R17/R19: scheduling tricks => stall/jitter). Only other
// change: in-place quad shfl pre-reduce (no arrays) -> part[512][9].
// 256 WGs x 512 thr, 1 per CU. WG = (dir, bg of 8 batches, 16-cell slice).

#define Bv 32
#define Tv 512
#define Dv 512
#define Hv 512
#define XS 520            // x LDS row stride
#define HS 520            // h LDS row stride
#define PUN 4608          // union: max(8*HS=4160, 512*9=4608) floats

__device__ __forceinline__ float sigmf_(float x) { return 1.0f / (1.0f + __expf(-x)); }
__device__ __forceinline__ float tanhf_(float x) { return 2.0f / (1.0f + __expf(-2.0f * x)) - 1.0f; }

// L2-visible poll load: bypass L1 (sc0), hit the shared XCD L2.
__device__ __forceinline__ unsigned int l2_load_u32(const unsigned int* p) {
    unsigned int v;
    asm volatile("global_load_dword %0, %1, off sc0\n\t"
                 "s_waitcnt vmcnt(0)"
                 : "=v"(v) : "v"(p) : "memory");
    return v;
}

__global__ __launch_bounds__(512, 2) void bilstm_coop10(
    const float* __restrict__ x, const int* __restrict__ lengths,
    const float* __restrict__ Wih_f, const float* __restrict__ Whh_f,
    const float* __restrict__ bih_f, const float* __restrict__ bhh_f,
    const float* __restrict__ Wih_b, const float* __restrict__ Whh_b,
    const float* __restrict__ bih_b, const float* __restrict__ bhh_b,
    float* __restrict__ out, unsigned int* __restrict__ cnt)  // cnt: 8 groups x 64 u32
{
    __shared__ float xb[8 * XS];       // 16.6 KB
    __shared__ float hu[PUN];          // 18.4 KB (h stage / part[512][9] union)
    __shared__ float gates[64 * 9];    // 2.3 KB
    __shared__ float bias_s[64];

    const int tid = threadIdx.x;
    const int w   = blockIdx.x;

    // group == XCD (w & 7): all 32 WGs of a pipeline share one L2.
    // XCDs 0..3 -> dir 0 (bg 0..3), XCDs 4..7 -> dir 1.
    const int xcd    = w & 7;
    const int dir    = xcd >> 2;
    const int bg     = xcd & 3;
    const int cslice = w >> 3;          // 0..31
    const int c0     = cslice * 16;     // first of 16 cells
    const int b0     = bg * 8;          // first of 8 batches
    const int group  = xcd;

    unsigned int* myslot = cnt + (size_t)group * 64 + cslice;

    const float* Wih = dir ? Wih_b : Wih_f;
    const float* Whh = dir ? Whh_b : Whh_f;
    const float* bih = dir ? bih_b : bih_f;
    const float* bhh = dir ? bhh_b : bhh_f;

    // ---- prologue ----
    if (tid == 0) {
        *(volatile unsigned int*)myslot = 0u;   // shared-L2 copy
        __hip_atomic_store(myslot, 0u, __ATOMIC_RELAXED, __HIP_MEMORY_SCOPE_AGENT);
    }
    if (tid < 64) {
        int gate = tid >> 4, cell = tid & 15;
        int rg = gate * Hv + c0 + cell;
        bias_s[tid] = bih[rg] + bhh[rg];
    }
    cg::this_grid().sync();   // once per launch: slots zeroed + visible

    // thread tile: pos = 4 gate-rows, 8 batches, 32-float k-segment (== R15)
    const int pos  = tid >> 5;      // 0..15 -> rows pos*4 .. pos*4+3 (of 64)
    const int kseg = tid & 31;      // 0..31

    int wrow[4];
    #pragma unroll
    for (int i = 0; i < 4; ++i) {
        int r = pos * 4 + i;                     // 0..63
        wrow[i] = (r >> 4) * Hv + c0 + (r & 15); // gate*H + cell
    }

    // step-invariant Whh slice in registers (16 x float4 = 64 VGPR, == R15)
    float4 whr[4][4];
    #pragma unroll
    for (int j = 0; j < 4; ++j)
        #pragma unroll
        for (int i = 0; i < 4; ++i)
            whr[j][i] = *(const float4*)(Whh + (size_t)wrow[i] * Dv
                                             + (j * 32 + kseg) * 4);

    // tail state: tid<128 -> (ib = tid>>4, cell = tid&15)
    const int pw_ib   = tid >> 4;   // 0..7 (valid when tid<128)
    const int pw_cell = tid & 15;
    float cst_r = 0.0f;
    int   len_r = 0;
    if (tid < 128) len_r = lengths[b0 + pw_ib];

    float* part = hu;   // alias (dump 512*9*4 = 18.4 KB)

    for (int s = 0; s < Tv; ++s) {
        const int t = dir ? (Tv - 1 - s) : s;

        // ---- 1. stage x_t (2 float4 per thread; shared via XCD L2) ----
        #pragma unroll
        for (int j = 0; j < 2; ++j) {
            int F  = tid + j * 512;            // 0..1023 f4-slots
            int bl = F >> 7, cf = F & 127;
            *(float4*)(xb + bl * XS + cf * 4) =
                *(const float4*)(x + ((size_t)(b0 + bl) * Tv + t) * Dv + cf * 4);
        }
        __syncthreads();   // [A]

        // ---- 2. x-part GEMM (covers flag propagation of step s-1) ----
        float acc[4][8];
        #pragma unroll
        for (int i = 0; i < 4; ++i)
            #pragma unroll
            for (int ib = 0; ib < 8; ++ib) acc[i][ib] = 0.0f;

        #pragma unroll
        for (int j = 0; j < 4; ++j) {
            const int col = (j * 32 + kseg) * 4;
            float4 wv[4];
            #pragma unroll
            for (int i = 0; i < 4; ++i)
                wv[i] = *(const float4*)(Wih + (size_t)wrow[i] * Dv + col);
            float4 xv[8];
            #pragma unroll
            for (int ib = 0; ib < 8; ++ib)
                xv[ib] = *(const float4*)(xb + ib * XS + col);
            #pragma unroll
            for (int i = 0; i < 4; ++i)
                #pragma unroll
                for (int ib = 0; ib < 8; ++ib)
                    acc[i][ib] += wv[i].x * xv[ib].x + wv[i].y * xv[ib].y
                                + wv[i].z * xv[ib].z + wv[i].w * xv[ib].w;
        }

        // ---- 3. WAIT: tid<32 poll the group's 32 slots via shared-L2 sc0
        //         loads; agent-scope check every 64 spins (mapping net) ----
        if (s > 0 && tid < 32) {
            const unsigned int tgt = (unsigned int)s;
            const unsigned int* sl = cnt + (size_t)group * 64 + tid;
            int spins = 0;
            for (;;) {
                unsigned int v = l2_load_u32(sl);
                if (v >= tgt) break;
                if ((++spins & 63) == 0) {
                    v = __hip_atomic_load(sl, __ATOMIC_RELAXED,
                                          __HIP_MEMORY_SCOPE_AGENT);
                    if (v >= tgt) break;
                }
                __builtin_amdgcn_s_sleep(1);
            }
        }
        __syncthreads();   // [B]

        // ---- 4. stage h_{s-1} from out: fresh addresses; writer's dirty
        //         lines live in THIS XCD's L2 -> L2 hit (LLC if mapping off)
        if (s == 0) {
            #pragma unroll
            for (int j = 0; j < 2; ++j) {
                int F  = tid + j * 512;
                int bl = F >> 7, cf = F & 127;
                *(float4*)(hu + bl * HS + cf * 4) = make_float4(0.f, 0.f, 0.f, 0.f);
            }
        } else {
            const int tp = dir ? (t + 1) : (t - 1);
            #pragma unroll
            for (int j = 0; j < 2; ++j) {
                int F  = tid + j * 512;
                int bl = F >> 7, cf = F & 127;
                *(float4*)(hu + bl * HS + cf * 4) =
                    *(const float4*)(out + ((size_t)(b0 + bl) * Tv + tp) * (2 * Hv)
                                         + dir * Hv + cf * 4);
            }
        }
        __syncthreads();   // [C]

        // hold-value for masked batches (read before hu is aliased)
        float hpv = 0.0f;
        if (tid < 128) hpv = hu[pw_ib * HS + c0 + pw_cell];

        // ---- 5. h-part GEMM: pure LDS + register weights ----
        #pragma unroll
        for (int j = 0; j < 4; ++j) {
            const int col = (j * 32 + kseg) * 4;
            float4 hv[8];
            #pragma unroll
            for (int ib = 0; ib < 8; ++ib)
                hv[ib] = *(const float4*)(hu + ib * HS + col);
            #pragma unroll
            for (int i = 0; i < 4; ++i)
                #pragma unroll
                for (int ib = 0; ib < 8; ++ib)
                    acc[i][ib] += whr[j][i].x * hv[ib].x + whr[j][i].y * hv[ib].y
                                + whr[j][i].z * hv[ib].z + whr[j][i].w * hv[ib].w;
        }
        __syncthreads();   // [D] hu reads + hpv done; alias as part[512][9]

        // ---- 6. IN-PLACE quad pre-reduce (kseg^1,^2) + dump (kseg%4==0) ----
        #pragma unroll
        for (int i = 0; i < 4; ++i)
            #pragma unroll
            for (int ib = 0; ib < 8; ++ib) {
                float v = acc[i][ib];
                v += __shfl_xor(v, 1, 64);
                v += __shfl_xor(v, 2, 64);
                acc[i][ib] = v;
            }
        if ((kseg & 3) == 0) {
            const int q = kseg >> 2;           // 0..7
            #pragma unroll
            for (int i = 0; i < 4; ++i) {
                const int r = pos * 4 + i;
                #pragma unroll
                for (int ib = 0; ib < 8; ++ib)
                    part[(r * 8 + ib) * 9 + q] = acc[i][ib];
            }
        }
        __syncthreads();   // [E]

        // ---- 7. final reduce (8 quads) + bias -> gates[row][ib] ----
        {
            const float* pr = part + tid * 9;  // row*8+ib == tid (0..511)
            float s0 = (pr[0] + pr[1]) + (pr[2] + pr[3]);
            float s1 = (pr[4] + pr[5]) + (pr[6] + pr[7]);
            gates[(tid >> 3) * 9 + (tid & 7)] = s0 + s1 + bias_s[tid >> 3];
        }
        __syncthreads();   // [F]

        // ---- 8. tail (tid<128): pointwise + PLAIN cached publish ----
        // Dirty lines stay in the shared XCD L2 for next step's readers;
        // the RELEASE arrive below writes them back to LLC (net + final out).
        if (tid < 128) {
            float gi = sigmf_(gates[(0 * 16 + pw_cell) * 9 + pw_ib]);
            float gf = sigmf_(gates[(1 * 16 + pw_cell) * 9 + pw_ib]);
            float gg = tanhf_(gates[(2 * 16 + pw_cell) * 9 + pw_ib]);
            float go = sigmf_(gates[(3 * 16 + pw_cell) * 9 + pw_ib]);
            float cn = gf * cst_r + gi * gg;
            float hn = go * tanhf_(cn);
            const bool vld = (t < len_r);
            float ho = vld ? hn : hpv;
            cst_r = vld ? cn : cst_r;
            out[((size_t)(b0 + pw_ib) * Tv + t) * (2 * Hv) + dir * Hv + c0 + pw_cell]
                = ho;
        }
        __syncthreads();   // [G] all publish stores reached L2 (vmcnt drained)

        // ---- 9. ARRIVE: plain flag to shared L2 (fast path), then RELEASE
        //         agent store (wbl2 -> h current in LLC; cross-XCD net) ----
        if (tid == 0) {
            *(volatile unsigned int*)myslot = (unsigned int)(s + 1);
            __hip_atomic_store(myslot, (unsigned int)(s + 1),
                               __ATOMIC_RELEASE, __HIP_MEMORY_SCOPE_AGENT);
        }
    }
}

// ---------------- fallback: R10 kernel (unchanged, correct, slow) ----------------
__global__ __launch_bounds__(1024, 1) void bilstm_simple(
    const float* __restrict__ x,
    const int* __restrict__ lengths,
    const float* __restrict__ Wih_f, const float* __restrict__ Whh_f,
    const float* __restrict__ bih_f, const float* __restrict__ bhh_f,
    const float* __restrict__ Wih_b, const float* __restrict__ Whh_b,
    const float* __restrict__ bih_b, const float* __restrict__ bhh_b,
    float* __restrict__ out)
{
    __shared__ float xh[Dv + Hv];
    __shared__ float cst[Hv];
    __shared__ float gates[4 * Hv];
    __shared__ float bias[4 * Hv];

    const int tid  = threadIdx.x;
    const int wave = tid >> 6;
    const int lane = tid & 63;
    const int dir  = blockIdx.x >> 5;
    const int b    = blockIdx.x & 31;

    const float* Wih = dir ? Wih_b : Wih_f;
    const float* Whh = dir ? Whh_b : Whh_f;
    const float* bih = dir ? bih_b : bih_f;
    const float* bhh = dir ? bhh_b : bhh_f;

    for (int i = tid; i < 4 * Hv; i += 1024) bias[i] = bih[i] + bhh[i];
    for (int i = tid; i < Hv; i += 1024) { xh[Dv + i] = 0.f; cst[i] = 0.f; }
    const int len = lengths[b];

    const float* Wbase = (lane < 32) ? Wih : Whh;
    const int koff = (lane & 31) * 16;

    for (int s = 0; s < Tv; ++s) {
        const int t = dir ? (Tv - 1 - s) : s;
        __syncthreads();
        for (int i = tid; i < Dv; i += 1024)
            xh[i] = x[((size_t)b * Tv + t) * Dv + i];
        __syncthreads();

        float4 xr0 = *(const float4*)(xh + lane * 16 + 0);
        float4 xr1 = *(const float4*)(xh + lane * 16 + 4);
        float4 xr2 = *(const float4*)(xh + lane * 16 + 8);
        float4 xr3 = *(const float4*)(xh + lane * 16 + 12);

        #pragma unroll 4
        for (int rr = 0; rr < 128; ++rr) {
            const int row = wave * 128 + rr;
            const float4* wr = (const float4*)(Wbase + (size_t)row * 512 + koff);
            const float4 w0 = wr[0], w1 = wr[1], w2 = wr[2], w3 = wr[3];
            float acc = w0.x * xr0.x + w0.y * xr0.y + w0.z * xr0.z + w0.w * xr0.w
                      + w1.x * xr1.x + w1.y * xr1.y + w1.z * xr1.z + w1.w * xr1.w
                      + w2.x * xr2.x + w2.y * xr2.y + w2.z * xr2.z + w2.w * xr2.w
                      + w3.x * xr3.x + w3.y * xr3.y + w3.z * xr3.z + w3.w * xr3.w;
            #pragma unroll
            for (int off = 32; off > 0; off >>= 1)
                acc += __shfl_xor(acc, off, 64);
            if (lane == 0) gates[row] = acc;
        }
        __syncthreads();

        if (tid < Hv) {
            const int cc = tid;
            const float gi = sigmf_(gates[0 * Hv + cc] + bias[0 * Hv + cc]);
            const float gf = sigmf_(gates[1 * Hv + cc] + bias[1 * Hv + cc]);
            const float gg = tanhf_(gates[2 * Hv + cc] + bias[2 * Hv + cc]);
            const float go = sigmf_(gates[3 * Hv + cc] + bias[3 * Hv + cc]);
            const float cn = gf * cst[cc] + gi * gg;
            const float hn = go * tanhf_(cn);
            const bool v = (t < len);
            const float hnew = v ? hn : xh[Dv + cc];
            cst[cc] = v ? cn : cst[cc];
            xh[Dv + cc] = hnew;
            out[((size_t)b * Tv + t) * (2 * Hv) + dir * Hv + cc] = hnew;
        }
    }
}

extern "C" void kernel_launch(void* const* d_in, const int* in_sizes, int n_in,
                              void* d_out, int out_size, void* d_ws, size_t ws_size,
                              hipStream_t stream) {
    (void)out_size;

    const void *xv, *len_p, *Wihf, *Whhf, *bihf, *bhhf, *Wihb, *Whhb, *bihb, *bhhb;
    if (n_in == 10 && in_sizes[9] == 8388608 && in_sizes[8] == 32) {
        // alphabetical pytree order fallback
        Whhb = d_in[0]; Whhf = d_in[1]; Wihb = d_in[2]; Wihf = d_in[3];
        bhhb = d_in[4]; bhhf = d_in[5]; bihb = d_in[6]; bihf = d_in[7];
        len_p = d_in[8]; xv = d_in[9];
    } else {
        // documented dict order
        xv = d_in[0]; len_p = d_in[1];
        Wihf = d_in[2]; Whhf = d_in[3]; bihf = d_in[4]; bhhf = d_in[5];
        Wihb = d_in[6]; Whhb = d_in[7]; bihb = d_in[8]; bhhb = d_in[9];
    }

    const float* xf  = (const float*)xv;
    const int*   lp  = (const int*)len_p;
    const float* wif = (const float*)Wihf;  const float* whf = (const float*)Whhf;
    const float* bif = (const float*)bihf;  const float* bhf = (const float*)bhhf;
    const float* wib = (const float*)Wihb;  const float* whb = (const float*)Whhb;
    const float* bib = (const float*)bihb;  const float* bhb = (const float*)bhhb;
    float* outp = (float*)d_out;
    unsigned int* cntp = (unsigned int*)d_ws;

    if (ws_size >= 8 * 64 * sizeof(unsigned int)) {   // 2 KB of slots
        void* args[12] = { &xf, &lp, &wif, &whf, &bif, &bhf,
                           &wib, &whb, &bib, &bhb, &outp, &cntp };
        hipError_t e = hipLaunchCooperativeKernel((const void*)bilstm_coop10,
                                                  dim3(256), dim3(512),
                                                  args, 0, stream);
        if (e == hipSuccess) return;
    }

    // fallback: R10 kernel
    bilstm_simple<<<dim3(64), dim3(1024), 0, stream>>>(
        xf, lp, wif, whf, bif, bhf, wib, whb, bib, bhb, outp);
}

// Round 11
// 6192.229 us; speedup vs baseline: 3.7599x; 1.5971x over previous
//
#include <hip/hip_runtime.h>
#include <hip/hip_cooperative_groups.h>

namespace cg = cooperative_groups;

// R21: R15 (proven 5.32ms) + exactly two validated, register-neutral trims:
//  (1) in-place quad shfl pre-reduce (R20-verified numerics, no arrays):
//      dump part[512][33] -> part[512][9], 4x less LDS dump traffic.
//  (2) x double-buffer prefetch (R17 component): stage x(s+1) AFTER the
//      x-GEMM; removes sync [A] + x-stage wait from the critical path.
// Exchange protocol, grid, register budget byte-identical to R15:
// 256 WGs x 512 thr (1/CU); WG = (dir, bg of 8 batches, 16-cell slice);
// 8 independent (dir,bg) pipelines x 32 WGs; sc1 publish into out[t];
// packed 4B flag slots, plain RELEASE arrive, 32-thread agent poll;
// no RMW in loop, no cache-wide fences; Whh slice in registers.

#define Bv 32
#define Tv 512
#define Dv 512
#define Hv 512
#define XS 520            // x LDS row stride (floats)
#define HS 520            // h LDS row stride
#define PUN 4608          // union: max(8*HS=4160, 512*9=4608) floats

__device__ __forceinline__ float sigmf_(float x) { return 1.0f / (1.0f + __expf(-x)); }
__device__ __forceinline__ float tanhf_(float x) { return 2.0f / (1.0f + __expf(-2.0f * x)) - 1.0f; }

__global__ __launch_bounds__(512, 2) void bilstm_coop11(
    const float* __restrict__ x, const int* __restrict__ lengths,
    const float* __restrict__ Wih_f, const float* __restrict__ Whh_f,
    const float* __restrict__ bih_f, const float* __restrict__ bhh_f,
    const float* __restrict__ Wih_b, const float* __restrict__ Whh_b,
    const float* __restrict__ bih_b, const float* __restrict__ bhh_b,
    float* __restrict__ out, unsigned int* __restrict__ cnt)  // cnt: 8 groups x 64 u32
{
    __shared__ float xb[2][8 * XS];    // double-buffered x stage (33.3 KB)
    __shared__ float hu[PUN];          // h stage / part[512][9] union (18.4 KB)
    __shared__ float gates[64 * 9];    // [row 64][b 8] pad 9
    __shared__ float bias_s[64];

    const int tid  = threadIdx.x;
    const int w    = blockIdx.x;

    // blockIdx -> XCD is (w & 7). XCDs 0..3 = dir 0, XCDs 4..7 = dir 1.
    // cslice is XCD-local (8 per XCD) -> per-XCD Wih slice = 1MB, L2-resident.
    const int xcd    = w & 7;
    const int slot   = w >> 3;                      // 0..31
    const int dir    = xcd >> 2;
    const int cslice = (xcd & 3) * 8 + (slot & 7);  // 0..31
    const int bg     = slot >> 3;                   // 0..3
    const int c0     = cslice * 16;                 // first of 16 cells
    const int b0     = bg * 8;                      // first of 8 batches
    const int group  = dir * 4 + bg;                // 0..7

    unsigned int* myslot = cnt + (size_t)group * 64 + cslice;  // packed 4B slots

    const float* Wih = dir ? Wih_b : Wih_f;
    const float* Whh = dir ? Whh_b : Whh_f;
    const float* bih = dir ? bih_b : bih_f;
    const float* bhh = dir ? bhh_b : bhh_f;

    // ---- prologue ----
    if (tid == 0)
        __hip_atomic_store(myslot, 0u, __ATOMIC_RELAXED, __HIP_MEMORY_SCOPE_AGENT);
    if (tid < 64) {
        int g = tid >> 4, cell = tid & 15;
        int rg = g * Hv + c0 + cell;
        bias_s[tid] = bih[rg] + bhh[rg];
    }
    // stage x(s=0) into xb[0]
    {
        const int t0 = dir ? (Tv - 1) : 0;
        #pragma unroll
        for (int j = 0; j < 2; ++j) {
            int F  = tid + j * 512;
            int bl = F >> 7, cf = F & 127;
            *(float4*)(&xb[0][bl * XS + cf * 4]) =
                *(const float4*)(x + ((size_t)(b0 + bl) * Tv + t0) * Dv + cf * 4);
        }
    }
    cg::this_grid().sync();   // once per launch: slots zeroed + xb[0] ready

    // thread tile: pos = 4 gate-rows, all 8 batches, 32-float k-segment
    const int pos  = tid >> 5;      // 0..15 -> rows pos*4 .. pos*4+3 (of 64)
    const int kseg = tid & 31;      // 0..31

    int wrow[4];
    #pragma unroll
    for (int i = 0; i < 4; ++i) {
        int r = pos * 4 + i;                 // 0..63
        wrow[i] = (r >> 4) * Hv + c0 + (r & 15);
    }

    // step-invariant Whh slice in registers (16 x float4 = 64 VGPR, == R15)
    float4 whr[4][4];
    #pragma unroll
    for (int j = 0; j < 4; ++j)
        #pragma unroll
        for (int i = 0; i < 4; ++i)
            whr[j][i] = *(const float4*)(Whh + (size_t)wrow[i] * Dv
                                             + (j * 32 + kseg) * 4);

    // tail state (threads 0..127: ib = tid>>4, cell = tid&15)
    const int pw_ib   = tid >> 4;    // 0..7  (valid when tid<128)
    const int pw_cell = tid & 15;    // 0..15
    float cst_r = 0.0f;
    int   len_r = 0;
    if (tid < 128) len_r = lengths[b0 + pw_ib];

    float* part = hu;   // alias (dump 512*9*4 = 18.4 KB)

    for (int s = 0; s < Tv; ++s) {
        const int t   = dir ? (Tv - 1 - s) : s;
        const int cur = s & 1;

        // ---- 1. x-part GEMM from xb[cur] (staged last iteration) ----
        float acc[4][8];
        #pragma unroll
        for (int i = 0; i < 4; ++i)
            #pragma unroll
            for (int ib = 0; ib < 8; ++ib) acc[i][ib] = 0.0f;

        #pragma unroll
        for (int j = 0; j < 4; ++j) {
            const int col = (j * 32 + kseg) * 4;    // float col 0..511
            float4 wv[4];
            #pragma unroll
            for (int i = 0; i < 4; ++i)
                wv[i] = *(const float4*)(Wih + (size_t)wrow[i] * Dv + col);
            float4 xv[8];
            #pragma unroll
            for (int ib = 0; ib < 8; ++ib)
                xv[ib] = *(const float4*)(&xb[cur][ib * XS + col]);
            #pragma unroll
            for (int i = 0; i < 4; ++i)
                #pragma unroll
                for (int ib = 0; ib < 8; ++ib)
                    acc[i][ib] += wv[i].x * xv[ib].x + wv[i].y * xv[ib].y
                                + wv[i].z * xv[ib].z + wv[i].w * xv[ib].w;
        }

        // ---- 2. prefetch x(s+1) into xb[cur^1] (off critical path) ----
        if (s + 1 < Tv) {
            const int tn = dir ? (Tv - 2 - s) : (s + 1);
            #pragma unroll
            for (int j = 0; j < 2; ++j) {
                int F  = tid + j * 512;
                int bl = F >> 7, cf = F & 127;
                *(float4*)(&xb[cur ^ 1][bl * XS + cf * 4]) =
                    *(const float4*)(x + ((size_t)(b0 + bl) * Tv + tn) * Dv + cf * 4);
            }
        }

        // ---- 3. WAIT: 32 threads poll 32 packed slots (2 lines/round) ----
        if (s > 0 && tid < 32) {
            const unsigned int tgt = (unsigned int)s;
            const unsigned int* sl = cnt + (size_t)group * 64 + tid;
            while (__hip_atomic_load(sl, __ATOMIC_RELAXED,
                                     __HIP_MEMORY_SCOPE_AGENT) < tgt)
                __builtin_amdgcn_s_sleep(1);
        }
        __syncthreads();   // [B] barrier passed; xb[cur^1] also complete

        // ---- 4. stage h_{s-1} from out (fresh addresses -> L2 miss -> LLC) ----
        if (s == 0) {
            #pragma unroll
            for (int j = 0; j < 2; ++j) {
                int F  = tid + j * 512;
                int bl = F >> 7, cf = F & 127;
                *(float4*)(hu + bl * HS + cf * 4) = make_float4(0.f, 0.f, 0.f, 0.f);
            }
        } else {
            const int tp = dir ? (t + 1) : (t - 1);
            #pragma unroll
            for (int j = 0; j < 2; ++j) {
                int F  = tid + j * 512;
                int bl = F >> 7, cf = F & 127;
                *(float4*)(hu + bl * HS + cf * 4) =
                    *(const float4*)(out + ((size_t)(b0 + bl) * Tv + tp) * (2 * Hv)
                                         + dir * Hv + cf * 4);
            }
        }
        __syncthreads();   // [C] hu ready

        // hold-value for masked batches (read before hu is reused as part)
        float hpv = 0.0f;
        if (tid < 128) hpv = hu[pw_ib * HS + c0 + pw_cell];

        // ---- 5. h-part GEMM: pure LDS + register weights ----
        #pragma unroll
        for (int j = 0; j < 4; ++j) {
            const int col = (j * 32 + kseg) * 4;
            float4 hv[8];
            #pragma unroll
            for (int ib = 0; ib < 8; ++ib)
                hv[ib] = *(const float4*)(hu + ib * HS + col);
            #pragma unroll
            for (int i = 0; i < 4; ++i)
                #pragma unroll
                for (int ib = 0; ib < 8; ++ib)
                    acc[i][ib] += whr[j][i].x * hv[ib].x + whr[j][i].y * hv[ib].y
                                + whr[j][i].z * hv[ib].z + whr[j][i].w * hv[ib].w;
        }
        __syncthreads();   // [D] hu reads + hpv done; alias as part[512][9]

        // ---- 6. IN-PLACE quad pre-reduce (kseg^1,^2) + dump (kseg%4==0) ----
        #pragma unroll
        for (int i = 0; i < 4; ++i)
            #pragma unroll
            for (int ib = 0; ib < 8; ++ib) {
                float v = acc[i][ib];
                v += __shfl_xor(v, 1, 64);
                v += __shfl_xor(v, 2, 64);
                acc[i][ib] = v;
            }
        if ((kseg & 3) == 0) {
            const int q = kseg >> 2;           // 0..7
            #pragma unroll
            for (int i = 0; i < 4; ++i) {
                const int r = pos * 4 + i;     // 0..63
                #pragma unroll
                for (int ib = 0; ib < 8; ++ib)
                    part[(r * 8 + ib) * 9 + q] = acc[i][ib];
            }
        }
        __syncthreads();   // [E]

        // ---- 7. final reduce (8 quads) + bias -> gates[row][ib] ----
        {
            const float* pr = part + tid * 9;  // row*8+ib == tid (0..511)
            float s0 = (pr[0] + pr[1]) + (pr[2] + pr[3]);
            float s1 = (pr[4] + pr[5]) + (pr[6] + pr[7]);
            gates[(tid >> 3) * 9 + (tid & 7)] = s0 + s1 + bias_s[tid >> 3];
        }
        __syncthreads();   // [F] gates ready

        // ---- 8. tail (tid<128): pointwise, coalesced sc1 publish ----
        if (tid < 128) {
            float gi = sigmf_(gates[( 0 + pw_cell) * 9 + pw_ib]);
            float gf = sigmf_(gates[(16 + pw_cell) * 9 + pw_ib]);
            float gg = tanhf_(gates[(32 + pw_cell) * 9 + pw_ib]);
            float go = sigmf_(gates[(48 + pw_cell) * 9 + pw_ib]);
            float cn = gf * cst_r + gi * gg;
            float hn = go * tanhf_(cn);
            const bool vld = (t < len_r);
            float ho = vld ? hn : hpv;
            cst_r = vld ? cn : cst_r;
            // consecutive tid -> consecutive cell -> 64B-line coalesced
            __hip_atomic_store(out + ((size_t)(b0 + pw_ib) * Tv + t) * (2 * Hv)
                                   + dir * Hv + c0 + pw_cell,
                               ho, __ATOMIC_RELAXED, __HIP_MEMORY_SCOPE_AGENT);
        }
        __syncthreads();   // [G] all publish stores drained (vmcnt 0 at barrier)

        // ---- 9. ARRIVE: plain release store to own packed slot ----
        if (tid == 0)
            __hip_atomic_store(myslot, (unsigned int)(s + 1),
                               __ATOMIC_RELEASE, __HIP_MEMORY_SCOPE_AGENT);
    }
}

// ---------------- fallback: R10 kernel (unchanged, correct, slow) ----------------
__global__ __launch_bounds__(1024, 1) void bilstm_simple(
    const float* __restrict__ x,
    const int* __restrict__ lengths,
    const float* __restrict__ Wih_f, const float* __restrict__ Whh_f,
    const float* __restrict__ bih_f, const float* __restrict__ bhh_f,
    const float* __restrict__ Wih_b, const float* __restrict__ Whh_b,
    const float* __restrict__ bih_b, const float* __restrict__ bhh_b,
    float* __restrict__ out)
{
    __shared__ float xh[Dv + Hv];
    __shared__ float cst[Hv];
    __shared__ float gates[4 * Hv];
    __shared__ float bias[4 * Hv];

    const int tid  = threadIdx.x;
    const int wave = tid >> 6;
    const int lane = tid & 63;
    const int dir  = blockIdx.x >> 5;
    const int b    = blockIdx.x & 31;

    const float* Wih = dir ? Wih_b : Wih_f;
    const float* Whh = dir ? Whh_b : Whh_f;
    const float* bih = dir ? bih_b : bih_f;
    const float* bhh = dir ? bhh_b : bhh_f;

    for (int i = tid; i < 4 * Hv; i += 1024) bias[i] = bih[i] + bhh[i];
    for (int i = tid; i < Hv; i += 1024) { xh[Dv + i] = 0.f; cst[i] = 0.f; }
    const int len = lengths[b];

    const float* Wbase = (lane < 32) ? Wih : Whh;
    const int koff = (lane & 31) * 16;

    for (int s = 0; s < Tv; ++s) {
        const int t = dir ? (Tv - 1 - s) : s;
        __syncthreads();
        for (int i = tid; i < Dv; i += 1024)
            xh[i] = x[((size_t)b * Tv + t) * Dv + i];
        __syncthreads();

        float4 xr0 = *(const float4*)(xh + lane * 16 + 0);
        float4 xr1 = *(const float4*)(xh + lane * 16 + 4);
        float4 xr2 = *(const float4*)(xh + lane * 16 + 8);
        float4 xr3 = *(const float4*)(xh + lane * 16 + 12);

        #pragma unroll 4
        for (int rr = 0; rr < 128; ++rr) {
            const int row = wave * 128 + rr;
            const float4* wr = (const float4*)(Wbase + (size_t)row * 512 + koff);
            const float4 w0 = wr[0], w1 = wr[1], w2 = wr[2], w3 = wr[3];
            float acc = w0.x * xr0.x + w0.y * xr0.y + w0.z * xr0.z + w0.w * xr0.w
                      + w1.x * xr1.x + w1.y * xr1.y + w1.z * xr1.z + w1.w * xr1.w
                      + w2.x * xr2.x + w2.y * xr2.y + w2.z * xr2.z + w2.w * xr2.w
                      + w3.x * xr3.x + w3.y * xr3.y + w3.z * xr3.z + w3.w * xr3.w;
            #pragma unroll
            for (int off = 32; off > 0; off >>= 1)
                acc += __shfl_xor(acc, off, 64);
            if (lane == 0) gates[row] = acc;
        }
        __syncthreads();

        if (tid < Hv) {
            const int cc = tid;
            const float gi = sigmf_(gates[0 * Hv + cc] + bias[0 * Hv + cc]);
            const float gf = sigmf_(gates[1 * Hv + cc] + bias[1 * Hv + cc]);
            const float gg = tanhf_(gates[2 * Hv + cc] + bias[2 * Hv + cc]);
            const float go = sigmf_(gates[3 * Hv + cc] + bias[3 * Hv + cc]);
            const float cn = gf * cst[cc] + gi * gg;
            const float hn = go * tanhf_(cn);
            const bool v = (t < len);
            const float hnew = v ? hn : xh[Dv + cc];
            cst[cc] = v ? cn : cst[cc];
            xh[Dv + cc] = hnew;
            out[((size_t)b * Tv + t) * (2 * Hv) + dir * Hv + cc] = hnew;
        }
    }
}

extern "C" void kernel_launch(void* const* d_in, const int* in_sizes, int n_in,
                              void* d_out, int out_size, void* d_ws, size_t ws_size,
                              hipStream_t stream) {
    (void)out_size;

    const void *xv, *len_p, *Wihf, *Whhf, *bihf, *bhhf, *Wihb, *Whhb, *bihb, *bhhb;
    if (n_in == 10 && in_sizes[9] == 8388608 && in_sizes[8] == 32) {
        // alphabetical pytree order fallback
        Whhb = d_in[0]; Whhf = d_in[1]; Wihb = d_in[2]; Wihf = d_in[3];
        bhhb = d_in[4]; bhhf = d_in[5]; bihb = d_in[6]; bihf = d_in[7];
        len_p = d_in[8]; xv = d_in[9];
    } else {
        // documented dict order
        xv = d_in[0]; len_p = d_in[1];
        Wihf = d_in[2]; Whhf = d_in[3]; bihf = d_in[4]; bhhf = d_in[5];
        Wihb = d_in[6]; Whhb = d_in[7]; bihb = d_in[8]; bhhb = d_in[9];
    }

    const float* xf  = (const float*)xv;
    const int*   lp  = (const int*)len_p;
    const float* wif = (const float*)Wihf;  const float* whf = (const float*)Whhf;
    const float* bif = (const float*)bihf;  const float* bhf = (const float*)bhhf;
    const float* wib = (const float*)Wihb;  const float* whb = (const float*)Whhb;
    const float* bib = (const float*)bihb;  const float* bhb = (const float*)bhhb;
    float* outp = (float*)d_out;
    unsigned int* cntp = (unsigned int*)d_ws;

    if (ws_size >= 8 * 64 * sizeof(unsigned int)) {   // 2 KB of slots
        void* args[12] = { &xf, &lp, &wif, &whf, &bif, &bhf,
                           &wib, &whb, &bib, &bhb, &outp, &cntp };
        hipError_t e = hipLaunchCooperativeKernel((const void*)bilstm_coop11,
                                                  dim3(256), dim3(512),
                                                  args, 0, stream);
        if (e == hipSuccess) return;
    }

    // fallback: R10 kernel
    bilstm_simple<<<dim3(64), dim3(1024), 0, stream>>>(
        xf, lp, wif, whf, bif, bhf, wib, whb, bib, bhb, outp);
}

// Round 12
// 5408.317 us; speedup vs baseline: 4.3049x; 1.1449x over previous
//
#include <hip/hip_runtime.h>
#include <hip/hip_cooperative_groups.h>

namespace cg = cooperative_groups;

// R22 == R15 verbatim (session champion, 5.32 ms; 11.2x over session start).
// Cooperative weight-stationary BiLSTM, small independent barriers.
// 256 WGs x 512 thr (1/CU). WG = (dir, batch-group bg of 8 batches, 16-cell
// slice). 8 independent (dir,bg) pipelines of 32 WGs each. Per step:
//   stage x(8x512) -> x-GEMM -> wait(32 packed slots, 2 lines) ->
//   stage h(8x512, cached loads at fresh out addresses) -> h-GEMM (reg Whh)
//   -> partial reduce -> pointwise (128 thr, reg c-state) ->
//   publish h as FULL 64B lines (sc1) -> release own 4B slot.
// No RMW atomics in the loop, no cache-wide fences, weights L2-resident
// (per-XCD Wih slice 1MB via cslice-XCD mapping), Whh slice in registers.
// Post-R15 probes all regressed with attributed causes (R16/R18 VGPR spill,
// R17/R19 scheduling stall, R20 L2-writeback storm, R21 ds_swizzle cost):
// remaining ~6us/step is cross-XCD recurrence-exchange latency.

#define Bv 32
#define Tv 512
#define Dv 512
#define Hv 512
#define XS 520            // x LDS row stride (floats)
#define HS 520            // h LDS row stride
#define PUN 16896         // dword union: max(8*HS=4160, 512*33=16896)

__device__ __forceinline__ float sigmf_(float x) { return 1.0f / (1.0f + __expf(-x)); }
__device__ __forceinline__ float tanhf_(float x) { return 2.0f / (1.0f + __expf(-2.0f * x)) - 1.0f; }

__global__ __launch_bounds__(512, 2) void bilstm_coop5(
    const float* __restrict__ x, const int* __restrict__ lengths,
    const float* __restrict__ Wih_f, const float* __restrict__ Whh_f,
    const float* __restrict__ bih_f, const float* __restrict__ bhh_f,
    const float* __restrict__ Wih_b, const float* __restrict__ Whh_b,
    const float* __restrict__ bih_b, const float* __restrict__ bhh_b,
    float* __restrict__ out, unsigned int* __restrict__ cnt)  // cnt: 8 groups x 64 uints
{
    __shared__ float xb[8 * XS];       // x_t stage (8 batches x 512)
    __shared__ float hu[PUN];          // h stage / partial union
    __shared__ float gates[64 * 9];    // [row 64][b 8] pad 9
    __shared__ float bias_s[64];

    const int tid  = threadIdx.x;
    const int w    = blockIdx.x;

    // blockIdx -> XCD is (w & 7). XCDs 0..3 = dir 0, XCDs 4..7 = dir 1.
    // cslice is XCD-local (8 per XCD) so each XCD touches only 1MB of Wih.
    const int xcd    = w & 7;
    const int slot   = w >> 3;                    // 0..31
    const int dir    = xcd >> 2;
    const int cslice = (xcd & 3) * 8 + (slot & 7);  // 0..31
    const int bg     = slot >> 3;                   // 0..3
    const int c0     = cslice * 16;                 // first of 16 cells
    const int b0     = bg * 8;                      // first of 8 batches
    const int group  = dir * 4 + bg;                // 0..7

    unsigned int* myslot = cnt + (size_t)group * 64 + cslice;  // packed 4B slots

    const float* Wih = dir ? Wih_b : Wih_f;
    const float* Whh = dir ? Whh_b : Whh_f;
    const float* bih = dir ? bih_b : bih_f;
    const float* bhh = dir ? bhh_b : bhh_f;

    // ---- prologue ----
    if (tid == 0)
        __hip_atomic_store(myslot, 0u, __ATOMIC_RELAXED, __HIP_MEMORY_SCOPE_AGENT);
    if (tid < 64) {
        int g = tid >> 4, cell = tid & 15;
        int rg = g * Hv + c0 + cell;
        bias_s[tid] = bih[rg] + bhh[rg];
    }
    cg::this_grid().sync();   // once per launch: all slots zeroed + visible

    // thread tile: pos = 4 gate-rows, all 8 batches, 32-float k-segment
    const int pos  = tid >> 5;      // 0..15 -> rows pos*4 .. pos*4+3 (of 64)
    const int kseg = tid & 31;      // 0..31

    // global W row index for this thread's 4 rows
    int wrow[4];
    #pragma unroll
    for (int i = 0; i < 4; ++i) {
        int r = pos * 4 + i;                 // 0..63
        wrow[i] = (r >> 4) * Hv + c0 + (r & 15);
    }

    // ---- hoist step-invariant Whh slice into registers (16 x float4) ----
    float4 whr[4][4];
    #pragma unroll
    for (int j = 0; j < 4; ++j)
        #pragma unroll
        for (int i = 0; i < 4; ++i)
            whr[j][i] = *(const float4*)(Whh + (size_t)wrow[i] * Dv
                                             + (j * 32 + kseg) * 4);

    // ---- per-thread pointwise state (threads 0..127: ib = tid>>4, cell = tid&15) ----
    const int pw_ib   = tid >> 4;    // 0..7  (valid when tid<128)
    const int pw_cell = tid & 15;    // 0..15
    float cst_r = 0.0f;
    int   len_r = 0;
    if (tid < 128) len_r = lengths[b0 + pw_ib];

    for (int s = 0; s < Tv; ++s) {
        const int t = dir ? (Tv - 1 - s) : s;

        // ---- 1. stage x_t: 8 batches x 512 (2 float4 per thread) ----
        #pragma unroll
        for (int j = 0; j < 2; ++j) {
            int F  = tid + j * 512;           // 0..1023 f4-slots
            int bl = F >> 7, cf = F & 127;
            *(float4*)(xb + bl * XS + cf * 4) =
                *(const float4*)(x + ((size_t)(b0 + bl) * Tv + t) * Dv + cf * 4);
        }
        __syncthreads();   // [A] xb ready

        // ---- 2. x-part GEMM: acc[4 rows][8 batches] ----
        float acc[4][8];
        #pragma unroll
        for (int i = 0; i < 4; ++i)
            #pragma unroll
            for (int ib = 0; ib < 8; ++ib) acc[i][ib] = 0.0f;

        #pragma unroll
        for (int j = 0; j < 4; ++j) {
            const int col = (j * 32 + kseg) * 4;    // float col 0..511
            float4 wv[4];
            #pragma unroll
            for (int i = 0; i < 4; ++i)
                wv[i] = *(const float4*)(Wih + (size_t)wrow[i] * Dv + col);
            float4 xv[8];
            #pragma unroll
            for (int ib = 0; ib < 8; ++ib)
                xv[ib] = *(const float4*)(xb + ib * XS + col);
            #pragma unroll
            for (int i = 0; i < 4; ++i)
                #pragma unroll
                for (int ib = 0; ib < 8; ++ib)
                    acc[i][ib] += wv[i].x * xv[ib].x + wv[i].y * xv[ib].y
                                + wv[i].z * xv[ib].z + wv[i].w * xv[ib].w;
        }

        // ---- 3. WAIT: 32 threads poll 32 packed slots (2 lines/round) ----
        if (s > 0 && tid < 32) {
            const unsigned int tgt = (unsigned int)s;
            const unsigned int* sl = cnt + (size_t)group * 64 + tid;
            while (__hip_atomic_load(sl, __ATOMIC_RELAXED,
                                     __HIP_MEMORY_SCOPE_AGENT) < tgt)
                __builtin_amdgcn_s_sleep(1);
        }
        __syncthreads();   // [B] barrier passed

        // ---- 4. stage h_{s-1} from out (fresh addresses -> L2 miss -> LLC) ----
        if (s == 0) {
            #pragma unroll
            for (int j = 0; j < 2; ++j) {
                int F  = tid + j * 512;
                int bl = F >> 7, cf = F & 127;
                *(float4*)(hu + bl * HS + cf * 4) = make_float4(0.f, 0.f, 0.f, 0.f);
            }
        } else {
            const int tp = dir ? (t + 1) : (t - 1);
            #pragma unroll
            for (int j = 0; j < 2; ++j) {
                int F  = tid + j * 512;
                int bl = F >> 7, cf = F & 127;
                *(float4*)(hu + bl * HS + cf * 4) =
                    *(const float4*)(out + ((size_t)(b0 + bl) * Tv + tp) * (2 * Hv)
                                         + dir * Hv + cf * 4);
            }
        }
        __syncthreads();   // [C] hu ready

        // hold-value for masked batches (read before hu is reused as partial)
        float hpv = 0.0f;
        if (tid < 128) hpv = hu[pw_ib * HS + c0 + pw_cell];

        // ---- 5. h-part GEMM: pure LDS + register weights ----
        #pragma unroll
        for (int j = 0; j < 4; ++j) {
            const int col = (j * 32 + kseg) * 4;
            float4 hv[8];
            #pragma unroll
            for (int ib = 0; ib < 8; ++ib)
                hv[ib] = *(const float4*)(hu + ib * HS + col);
            #pragma unroll
            for (int i = 0; i < 4; ++i)
                #pragma unroll
                for (int ib = 0; ib < 8; ++ib)
                    acc[i][ib] += whr[j][i].x * hv[ib].x + whr[j][i].y * hv[ib].y
                                + whr[j][i].z * hv[ib].z + whr[j][i].w * hv[ib].w;
        }
        __syncthreads();   // [D] hu reads + hpv done; alias as partial[512][33]

        // ---- 6. partial dump: part[(row*8+ib)][kseg], pad 33 ----
        float* part = hu;
        #pragma unroll
        for (int i = 0; i < 4; ++i) {
            const int r = pos * 4 + i;
            #pragma unroll
            for (int ib = 0; ib < 8; ++ib)
                part[(r * 8 + ib) * 33 + kseg] = acc[i][ib];
        }
        __syncthreads();   // [E]

        // ---- 7. final reduce + bias -> gates[row][ib] ----
        {
            const float* pr = part + tid * 33;   // row*8+ib == tid
            float s0 = 0.f, s1 = 0.f, s2 = 0.f, s3 = 0.f;
            #pragma unroll
            for (int m = 0; m < 32; m += 4) {
                s0 += pr[m + 0]; s1 += pr[m + 1]; s2 += pr[m + 2]; s3 += pr[m + 3];
            }
            gates[(tid >> 3) * 9 + (tid & 7)] =
                ((s0 + s1) + (s2 + s3)) + bias_s[tid >> 3];
        }
        __syncthreads();   // [F] gates ready

        // ---- 8. pointwise (128 thr), publish full 64B lines via sc1 ----
        if (tid < 128) {
            float gi = sigmf_(gates[( 0 + pw_cell) * 9 + pw_ib]);
            float gf = sigmf_(gates[(16 + pw_cell) * 9 + pw_ib]);
            float gg = tanhf_(gates[(32 + pw_cell) * 9 + pw_ib]);
            float go = sigmf_(gates[(48 + pw_cell) * 9 + pw_ib]);
            float cn = gf * cst_r + gi * gg;
            float hn = go * tanhf_(cn);
            const bool v = (t < len_r);
            float ho = v ? hn : hpv;
            cst_r = v ? cn : cst_r;
            // consecutive tid -> consecutive cell -> 64B-line coalesced
            __hip_atomic_store(out + ((size_t)(b0 + pw_ib) * Tv + t) * (2 * Hv)
                                   + dir * Hv + c0 + pw_cell,
                               ho, __ATOMIC_RELAXED, __HIP_MEMORY_SCOPE_AGENT);
        }
        __syncthreads();   // [G] all publish stores drained (vmcnt 0 at barrier)

        // ---- 9. ARRIVE: plain release store to own packed slot ----
        if (tid == 0)
            __hip_atomic_store(myslot, (unsigned int)(s + 1),
                               __ATOMIC_RELEASE, __HIP_MEMORY_SCOPE_AGENT);
    }
}

// ---------------- fallback: R10 kernel (unchanged, correct, slow) ----------------
__global__ __launch_bounds__(1024, 1) void bilstm_simple(
    const float* __restrict__ x,
    const int* __restrict__ lengths,
    const float* __restrict__ Wih_f, const float* __restrict__ Whh_f,
    const float* __restrict__ bih_f, const float* __restrict__ bhh_f,
    const float* __restrict__ Wih_b, const float* __restrict__ Whh_b,
    const float* __restrict__ bih_b, const float* __restrict__ bhh_b,
    float* __restrict__ out)
{
    __shared__ float xh[Dv + Hv];
    __shared__ float cst[Hv];
    __shared__ float gates[4 * Hv];
    __shared__ float bias[4 * Hv];

    const int tid  = threadIdx.x;
    const int wave = tid >> 6;
    const int lane = tid & 63;
    const int dir  = blockIdx.x >> 5;
    const int b    = blockIdx.x & 31;

    const float* Wih = dir ? Wih_b : Wih_f;
    const float* Whh = dir ? Whh_b : Whh_f;
    const float* bih = dir ? bih_b : bih_f;
    const float* bhh = dir ? bhh_b : bhh_f;

    for (int i = tid; i < 4 * Hv; i += 1024) bias[i] = bih[i] + bhh[i];
    for (int i = tid; i < Hv; i += 1024) { xh[Dv + i] = 0.f; cst[i] = 0.f; }
    const int len = lengths[b];

    const float* Wbase = (lane < 32) ? Wih : Whh;
    const int koff = (lane & 31) * 16;

    for (int s = 0; s < Tv; ++s) {
        const int t = dir ? (Tv - 1 - s) : s;
        __syncthreads();
        for (int i = tid; i < Dv; i += 1024)
            xh[i] = x[((size_t)b * Tv + t) * Dv + i];
        __syncthreads();

        float4 xr0 = *(const float4*)(xh + lane * 16 + 0);
        float4 xr1 = *(const float4*)(xh + lane * 16 + 4);
        float4 xr2 = *(const float4*)(xh + lane * 16 + 8);
        float4 xr3 = *(const float4*)(xh + lane * 16 + 12);

        #pragma unroll 4
        for (int rr = 0; rr < 128; ++rr) {
            const int row = wave * 128 + rr;
            const float4* wr = (const float4*)(Wbase + (size_t)row * 512 + koff);
            const float4 w0 = wr[0], w1 = wr[1], w2 = wr[2], w3 = wr[3];
            float acc = w0.x * xr0.x + w0.y * xr0.y + w0.z * xr0.z + w0.w * xr0.w
                      + w1.x * xr1.x + w1.y * xr1.y + w1.z * xr1.z + w1.w * xr1.w
                      + w2.x * xr2.x + w2.y * xr2.y + w2.z * xr2.z + w2.w * xr2.w
                      + w3.x * xr3.x + w3.y * xr3.y + w3.z * xr3.z + w3.w * xr3.w;
            #pragma unroll
            for (int off = 32; off > 0; off >>= 1)
                acc += __shfl_xor(acc, off, 64);
            if (lane == 0) gates[row] = acc;
        }
        __syncthreads();

        if (tid < Hv) {
            const int cc = tid;
            const float gi = sigmf_(gates[0 * Hv + cc] + bias[0 * Hv + cc]);
            const float gf = sigmf_(gates[1 * Hv + cc] + bias[1 * Hv + cc]);
            const float gg = tanhf_(gates[2 * Hv + cc] + bias[2 * Hv + cc]);
            const float go = sigmf_(gates[3 * Hv + cc] + bias[3 * Hv + cc]);
            const float cn = gf * cst[cc] + gi * gg;
            const float hn = go * tanhf_(cn);
            const bool v = (t < len);
            const float hnew = v ? hn : xh[Dv + cc];
            cst[cc] = v ? cn : cst[cc];
            xh[Dv + cc] = hnew;
            out[((size_t)b * Tv + t) * (2 * Hv) + dir * Hv + cc] = hnew;
        }
    }
}

extern "C" void kernel_launch(void* const* d_in, const int* in_sizes, int n_in,
                              void* d_out, int out_size, void* d_ws, size_t ws_size,
                              hipStream_t stream) {
    (void)out_size;

    const void *xv, *len_p, *Wihf, *Whhf, *bihf, *bhhf, *Wihb, *Whhb, *bihb, *bhhb;
    if (n_in == 10 && in_sizes[9] == 8388608 && in_sizes[8] == 32) {
        // alphabetical pytree order fallback
        Whhb = d_in[0]; Whhf = d_in[1]; Wihb = d_in[2]; Wihf = d_in[3];
        bhhb = d_in[4]; bhhf = d_in[5]; bihb = d_in[6]; bihf = d_in[7];
        len_p = d_in[8]; xv = d_in[9];
    } else {
        // documented dict order
        xv = d_in[0]; len_p = d_in[1];
        Wihf = d_in[2]; Whhf = d_in[3]; bihf = d_in[4]; bhhf = d_in[5];
        Wihb = d_in[6]; Whhb = d_in[7]; bihb = d_in[8]; bhhb = d_in[9];
    }

    const float* xf  = (const float*)xv;
    const int*   lp  = (const int*)len_p;
    const float* wif = (const float*)Wihf;  const float* whf = (const float*)Whhf;
    const float* bif = (const float*)bihf;  const float* bhf = (const float*)bhhf;
    const float* wib = (const float*)Wihb;  const float* whb = (const float*)Whhb;
    const float* bib = (const float*)bihb;  const float* bhb = (const float*)bhhb;
    float* outp = (float*)d_out;
    unsigned int* cntp = (unsigned int*)d_ws;

    if (ws_size >= 8 * 64 * sizeof(unsigned int)) {   // 2 KB of slots
        void* args[12] = { &xf, &lp, &wif, &whf, &bif, &bhf,
                           &wib, &whb, &bib, &bhb, &outp, &cntp };
        hipError_t e = hipLaunchCooperativeKernel((const void*)bilstm_coop5,
                                                  dim3(256), dim3(512),
                                                  args, 0, stream);
        if (e == hipSuccess) return;
    }

    // fallback: R10 kernel
    bilstm_simple<<<dim3(64), dim3(1024), 0, stream>>>(
        xf, lp, wif, whf, bif, bhf, wib, whb, bib, bhb, outp);
}